// Round 8
// baseline (316.803 us; speedup 1.0000x reference)
//
#include <hip/hip_runtime.h>
#include <hip/hip_bf16.h>

#define BATCH 4
#define SEQ   8192
#define CH    512
#define NHEAD 8
#define HDIM  64
#define KTOK  256
#define FOURC 2048

typedef __attribute__((ext_vector_type(8))) short bf16x8;
typedef __attribute__((ext_vector_type(4))) float f32x4;

#define GLOAD_LDS16(g, l)                                                      \
  __builtin_amdgcn_global_load_lds(                                            \
      (const __attribute__((address_space(1))) void*)(g),                      \
      (__attribute__((address_space(3))) void*)(l), 16, 0, 0)

__device__ __forceinline__ ushort bf16bits(float f) {
  __hip_bfloat16 b = __float2bfloat16(f);
  return *reinterpret_cast<ushort*>(&b);
}
__device__ __forceinline__ uint packbf2(float lo, float hi) {
  return (uint)bf16bits(lo) | ((uint)bf16bits(hi) << 16);
}

// ---------------- K0: W [512][2048] fp32 -> Wt [2048][512] bf16 ----------------
__global__ __launch_bounds__(256) void k_wt(
    const float* __restrict__ W, __hip_bfloat16* __restrict__ Wt) {
  __shared__ float tile[32][33];
  const int bx = blockIdx.x * 32;
  const int by = blockIdx.y * 32;
  const int t = threadIdx.x;
  const int r = t >> 5, c = t & 31;
#pragma unroll
  for (int it = 0; it < 4; ++it)
    tile[r + it * 8][c] = W[(size_t)(by + r + it * 8) * FOURC + bx + c];
  __syncthreads();
#pragma unroll
  for (int it = 0; it < 4; ++it) {
    int n = r + it * 8;
    Wt[(size_t)(bx + n) * CH + by + c] = __float2bfloat16(tile[c][n]);
  }
}

// ---------------- K0b: P [8192][256] fp32 -> Pt [256][8192] bf16 ----------------
__global__ __launch_bounds__(256) void k_pt(
    const float* __restrict__ P, __hip_bfloat16* __restrict__ Pt) {
  __shared__ float tile[32][33];
  const int n0 = blockIdx.x * 32, k0 = blockIdx.y * 32;
  const int t = threadIdx.x, r = t >> 5, c = t & 31;
#pragma unroll
  for (int i = 0; i < 4; ++i)
    tile[r + i * 8][c] = P[(size_t)(n0 + r + i * 8) * KTOK + k0 + c];
  __syncthreads();
#pragma unroll
  for (int i = 0; i < 4; ++i)
    Pt[(size_t)(k0 + r + i * 8) * SEQ + n0 + c] = __float2bfloat16(tile[c][r + i * 8]);
}

// ---------------- K0c: X fp32 -> Xb bf16 (flat stream) ----------------
__global__ __launch_bounds__(256) void k_xbf(
    const float* __restrict__ X, __hip_bfloat16* __restrict__ Xb) {
  size_t i = ((size_t)blockIdx.x * 256 + threadIdx.x) * 8;
  float4 a = *reinterpret_cast<const float4*>(&X[i]);
  float4 b = *reinterpret_cast<const float4*>(&X[i + 4]);
  ushort tmp[8];
  tmp[0] = bf16bits(a.x); tmp[1] = bf16bits(a.y);
  tmp[2] = bf16bits(a.z); tmp[3] = bf16bits(a.w);
  tmp[4] = bf16bits(b.x); tmp[5] = bf16bits(b.y);
  tmp[6] = bf16bits(b.z); tmp[7] = bf16bits(b.w);
  *reinterpret_cast<uint4*>(&Xb[i]) = *reinterpret_cast<const uint4*>(tmp);
}

// ---------------- K1: qkvv = Xb @ Wt, bf16 MFMA, 4-deep gload_lds pipeline ----------------
__global__ __launch_bounds__(256) void k_gemm_mfma(
    const __hip_bfloat16* __restrict__ Xb, const __hip_bfloat16* __restrict__ Wt,
    __hip_bfloat16* __restrict__ QKVV) {
  __shared__ __align__(16) __hip_bfloat16 As[4][128 * 32];
  __shared__ __align__(16) __hip_bfloat16 Bs[4][128 * 32];
  const int t = threadIdx.x;
  const int wid = t >> 6, lane = t & 63;
  const int bid = blockIdx.x;
  const int xcd = bid & 7;
  const int l = bid >> 3;
  const int bm = (xcd * 32 + (l >> 4)) * 128;
  const int bn = (l & 15) * 128;
  const int wr = wid >> 1, wc = wid & 1;
  const int lrow = lane & 15;
  const int lk = (((lane >> 4) ^ ((lrow >> 1) & 3))) * 8;
  const int srow = lane >> 2;
  const int sk8 = (((lane & 3) ^ ((lane >> 3) & 3))) * 8;
  const int c0 = wid * 2, c1 = wid * 2 + 1;
  f32x4 acc[4][4] = {};

#define STAGE(bufi, kk)                                                         \
  do {                                                                          \
    GLOAD_LDS16(&Xb[(size_t)(bm + c0 * 16 + srow) * CH + (kk) + sk8],           \
                &As[bufi][c0 * 512]);                                           \
    GLOAD_LDS16(&Wt[(size_t)(bn + c0 * 16 + srow) * CH + (kk) + sk8],           \
                &Bs[bufi][c0 * 512]);                                           \
    GLOAD_LDS16(&Xb[(size_t)(bm + c1 * 16 + srow) * CH + (kk) + sk8],           \
                &As[bufi][c1 * 512]);                                           \
    GLOAD_LDS16(&Wt[(size_t)(bn + c1 * 16 + srow) * CH + (kk) + sk8],           \
                &Bs[bufi][c1 * 512]);                                           \
  } while (0)

  STAGE(0, 0);
  STAGE(1, 32);
  STAGE(2, 64);
#pragma unroll
  for (int kt = 0; kt < 16; ++kt) {
    const int cur = kt & 3;
    if (kt < 13) {
      STAGE((kt + 3) & 3, (kt + 3) * 32);
      asm volatile("s_waitcnt vmcnt(12)" ::: "memory");
    } else if (kt == 13) {
      asm volatile("s_waitcnt vmcnt(8)" ::: "memory");
    } else if (kt == 14) {
      asm volatile("s_waitcnt vmcnt(4)" ::: "memory");
    } else {
      asm volatile("s_waitcnt vmcnt(0)" ::: "memory");
    }
    __builtin_amdgcn_s_barrier();
    bf16x8 af[4], bfr[4];
#pragma unroll
    for (int i = 0; i < 4; ++i)
      af[i] = *reinterpret_cast<const bf16x8*>(&As[cur][(wr * 64 + i * 16 + lrow) * 32 + lk]);
#pragma unroll
    for (int j = 0; j < 4; ++j)
      bfr[j] = *reinterpret_cast<const bf16x8*>(&Bs[cur][(wc * 64 + j * 16 + lrow) * 32 + lk]);
#pragma unroll
    for (int i = 0; i < 4; ++i)
#pragma unroll
      for (int j = 0; j < 4; ++j)
        acc[i][j] = __builtin_amdgcn_mfma_f32_16x16x32_bf16(af[i], bfr[j], acc[i][j], 0, 0, 0);
    asm volatile("s_waitcnt lgkmcnt(0)" ::: "memory");
    __builtin_amdgcn_s_barrier();
  }
#undef STAGE
  const int l4 = (lane >> 4) * 4;
#pragma unroll
  for (int i = 0; i < 4; ++i)
#pragma unroll
    for (int j = 0; j < 4; ++j) {
      int col = bn + wc * 64 + j * 16 + lrow;
#pragma unroll
      for (int r = 0; r < 4; ++r) {
        int row = bm + wr * 64 + i * 16 + l4 + r;
        QKVV[(size_t)row * FOURC + col] = __float2bfloat16(acc[i][j][r]);
      }
    }
}

// ---------------- K3: fused gram + sumsq + k/v projections (pipelined, 512-row slices) ----------------
__global__ __launch_bounds__(256) void k_qkstats(
    const __hip_bfloat16* __restrict__ QKVV,
    const __hip_bfloat16* __restrict__ Pt,
    float* __restrict__ G, float* __restrict__ sumsq, float* __restrict__ raw) {
  __shared__ __hip_bfloat16 qT[64][40];
  __shared__ __hip_bfloat16 kT[64][40];
  __shared__ __hip_bfloat16 vT[64][40];
  __shared__ __hip_bfloat16 pT[256][40];
  __shared__ float red[32][64];
  const int bh = blockIdx.y, b = bh >> 3, h = bh & 7;
  const int nbase = blockIdx.x * 512;
  const int t = threadIdx.x, w = t >> 6, lane = t & 63;
  const int l15 = lane & 15, g = lane >> 4;
  const int comp = w >> 1, kh = w & 1;
  const int srow = t >> 3, sdq = (t & 7) * 8;
  const int prow = t >> 2, poff = (t & 3) * 8;
  f32x4 acc[4][8] = {};
  f32x4 accg[4] = {};
  float sqq[8] = {}, sqk[8] = {};
  uint4 uq, uk, uv, up0, up1, up2, up3;
  {
    size_t gb = (size_t)(b * SEQ + nbase + srow) * FOURC + h * HDIM + sdq;
    uq = *reinterpret_cast<const uint4*>(&QKVV[gb]);
    uk = *reinterpret_cast<const uint4*>(&QKVV[gb + CH]);
    uv = *reinterpret_cast<const uint4*>(&QKVV[gb + 3 * CH]);
    up0 = *reinterpret_cast<const uint4*>(&Pt[(size_t)(0 * 64 + prow) * SEQ + nbase + poff]);
    up1 = *reinterpret_cast<const uint4*>(&Pt[(size_t)(1 * 64 + prow) * SEQ + nbase + poff]);
    up2 = *reinterpret_cast<const uint4*>(&Pt[(size_t)(2 * 64 + prow) * SEQ + nbase + poff]);
    up3 = *reinterpret_cast<const uint4*>(&Pt[(size_t)(3 * 64 + prow) * SEQ + nbase + poff]);
  }
  for (int it = 0; it < 16; ++it) {
    {
      const __hip_bfloat16* hq = reinterpret_cast<const __hip_bfloat16*>(&uq);
      const __hip_bfloat16* hk = reinterpret_cast<const __hip_bfloat16*>(&uk);
      const __hip_bfloat16* hv = reinterpret_cast<const __hip_bfloat16*>(&uv);
#pragma unroll
      for (int j = 0; j < 8; ++j) {
        float fq = __bfloat162float(hq[j]);
        float fk = __bfloat162float(hk[j]);
        sqq[j] = fmaf(fq, fq, sqq[j]);
        sqk[j] = fmaf(fk, fk, sqk[j]);
        qT[sdq + j][srow] = hq[j];
        kT[sdq + j][srow] = hk[j];
        vT[sdq + j][srow] = hv[j];
      }
      *reinterpret_cast<uint4*>(&pT[0 * 64 + prow][poff]) = up0;
      *reinterpret_cast<uint4*>(&pT[1 * 64 + prow][poff]) = up1;
      *reinterpret_cast<uint4*>(&pT[2 * 64 + prow][poff]) = up2;
      *reinterpret_cast<uint4*>(&pT[3 * 64 + prow][poff]) = up3;
    }
    if (it < 15) {
      const int nn = nbase + (it + 1) * 32;
      size_t gb = (size_t)(b * SEQ + nn + srow) * FOURC + h * HDIM + sdq;
      uq = *reinterpret_cast<const uint4*>(&QKVV[gb]);
      uk = *reinterpret_cast<const uint4*>(&QKVV[gb + CH]);
      uv = *reinterpret_cast<const uint4*>(&QKVV[gb + 3 * CH]);
      up0 = *reinterpret_cast<const uint4*>(&Pt[(size_t)(0 * 64 + prow) * SEQ + nn + poff]);
      up1 = *reinterpret_cast<const uint4*>(&Pt[(size_t)(1 * 64 + prow) * SEQ + nn + poff]);
      up2 = *reinterpret_cast<const uint4*>(&Pt[(size_t)(2 * 64 + prow) * SEQ + nn + poff]);
      up3 = *reinterpret_cast<const uint4*>(&Pt[(size_t)(3 * 64 + prow) * SEQ + nn + poff]);
    }
    __syncthreads();
    {
      bf16x8 Aq[4];
#pragma unroll
      for (int dt = 0; dt < 4; ++dt)
        Aq[dt] = *reinterpret_cast<const bf16x8*>(&qT[dt * 16 + l15][g * 8]);
      bf16x8 Bk = *reinterpret_cast<const bf16x8*>(&kT[w * 16 + l15][g * 8]);
#pragma unroll
      for (int dt = 0; dt < 4; ++dt)
        accg[dt] = __builtin_amdgcn_mfma_f32_16x16x32_bf16(Aq[dt], Bk, accg[dt], 0, 0, 0);
    }
    {
      bf16x8 A[4], B[8];
#pragma unroll
      for (int dt = 0; dt < 4; ++dt)
        A[dt] = comp ? *reinterpret_cast<const bf16x8*>(&vT[dt * 16 + l15][g * 8])
                     : *reinterpret_cast<const bf16x8*>(&kT[dt * 16 + l15][g * 8]);
#pragma unroll
      for (int kt = 0; kt < 8; ++kt)
        B[kt] = *reinterpret_cast<const bf16x8*>(&pT[(kh * 8 + kt) * 16 + l15][g * 8]);
#pragma unroll
      for (int dt = 0; dt < 4; ++dt)
#pragma unroll
        for (int kt = 0; kt < 8; ++kt)
          acc[dt][kt] = __builtin_amdgcn_mfma_f32_16x16x32_bf16(A[dt], B[kt], acc[dt][kt], 0, 0, 0);
    }
    __syncthreads();
  }
#pragma unroll
  for (int j = 0; j < 8; ++j) red[srow][sdq + j] = sqq[j];
  __syncthreads();
  if (t < 64) {
    float tot = 0.f;
#pragma unroll
    for (int r = 0; r < 32; ++r) tot += red[r][t];
    atomicAdd(&sumsq[bh * 64 + t], tot);
  }
  __syncthreads();
#pragma unroll
  for (int j = 0; j < 8; ++j) red[srow][sdq + j] = sqk[j];
  __syncthreads();
  if (t < 64) {
    float tot = 0.f;
#pragma unroll
    for (int r = 0; r < 32; ++r) tot += red[r][t];
    atomicAdd(&sumsq[2048 + bh * 64 + t], tot);
  }
  float* gp = G + (size_t)bh * 4096;
#pragma unroll
  for (int dt = 0; dt < 4; ++dt)
#pragma unroll
    for (int r = 0; r < 4; ++r)
      atomicAdd(&gp[(dt * 16 + g * 4 + r) * 64 + w * 16 + l15], accg[dt][r]);
  float* rp = raw + ((size_t)bh * 2 + comp) * (64 * 256);
#pragma unroll
  for (int dt = 0; dt < 4; ++dt)
#pragma unroll
    for (int kt = 0; kt < 8; ++kt)
#pragma unroll
      for (int r = 0; r < 4; ++r)
        atomicAdd(&rp[(dt * 16 + g * 4 + r) * 256 + (kh * 8 + kt) * 16 + l15],
                  acc[dt][kt][r]);
}

// ---------------- K4: merged epilogue: norms + CA softmax (bf16 out) + projfin ----------------
__global__ __launch_bounds__(256) void k_epi(
    const float* __restrict__ sumsq, const float* __restrict__ G,
    const float* __restrict__ raw, const float* __restrict__ tca,
    const float* __restrict__ tsa, __hip_bfloat16* __restrict__ Gb,
    __hip_bfloat16* __restrict__ kpT, __hip_bfloat16* __restrict__ vpT) {
  __shared__ float iqs[64], iks[64];
  __shared__ float tile[64][65];
  const int bh = blockIdx.x, h = bh & 7;
  const int t = threadIdx.x;
  if (t < 64) {
    iqs[t] = rsqrtf(fmaxf(sumsq[bh * 64 + t], 1e-6f));
    iks[t] = rsqrtf(fmaxf(sumsq[2048 + bh * 64 + t], 1e-6f));
  }
  __syncthreads();
  if (t < 64) {
    const float* row = G + (size_t)bh * 4096 + t * 64;
    const float s0 = iqs[t] * tca[h];
    float vals[64];
    float m = -3.0e38f;
#pragma unroll
    for (int e = 0; e < 64; ++e) {
      float v = row[e] * s0 * iks[e];
      vals[e] = v;
      m = fmaxf(m, v);
    }
    float s = 0.f;
#pragma unroll
    for (int e = 0; e < 64; ++e) { vals[e] = __expf(vals[e] - m); s += vals[e]; }
    float r = 1.0f / s;
#pragma unroll
    for (int e = 0; e < 64; ++e)
      Gb[(size_t)bh * 4096 + t * 64 + e] = __float2bfloat16(vals[e] * r);
  }
  const float ts = tsa[h];
  const float* r0 = raw + (size_t)bh * 2 * 16384;
  for (int kc = 0; kc < 4; ++kc) {
    __syncthreads();
    for (int i = t; i < 4096; i += 256) {
      int d = i >> 6, kk = i & 63;
      tile[d][kk] = r0[d * 256 + kc * 64 + kk];
    }
    __syncthreads();
    for (int i = t; i < 4096; i += 256) {
      int kk = i >> 6, d = i & 63;
      float sc = iqs[d] * iks[d] * ts;
      kpT[(size_t)bh * 16384 + (kc * 64 + kk) * 64 + d] = __float2bfloat16(tile[d][kk] * sc);
    }
  }
  const float* r1 = r0 + 16384;
  for (int i = t; i < 16384; i += 256)
    vpT[(size_t)bh * 16384 + i] = __float2bfloat16(r1[i]);
}

// ---------------- K7: fused output = x_ca + x_sa via MFMA (q/v prefetch) ----------------
__global__ __launch_bounds__(256) void k_xout(
    const __hip_bfloat16* __restrict__ QKVV,
    const __hip_bfloat16* __restrict__ Gb,
    const __hip_bfloat16* __restrict__ kpT,
    const __hip_bfloat16* __restrict__ vpT,
    float* __restrict__ out) {
  __shared__ __hip_bfloat16 vs[64][264];
  __shared__ __hip_bfloat16 ps[4][16][264];
  __shared__ __hip_bfloat16 gs[64][72];
  const int bh = blockIdx.y, b = bh >> 3, h = bh & 7;
  const int nblk = blockIdx.x * 512;
  const int t = threadIdx.x, w = t >> 6, lane = t & 63;
  const int l15 = lane & 15, g = lane >> 4;
  for (int i = t; i < 2048; i += 256) {
    int d = i >> 5, k8 = (i & 31) * 8;
    *reinterpret_cast<uint4*>(&vs[d][k8]) =
        *reinterpret_cast<const uint4*>(&vpT[((size_t)bh * 64 + d) * 256 + k8]);
  }
  for (int i = t; i < 512; i += 256) {
    int row = i >> 3, q = i & 7;
    *reinterpret_cast<uint4*>(&gs[row][q * 8]) =
        *reinterpret_cast<const uint4*>(&Gb[(size_t)bh * 4096 + row * 64 + q * 8]);
  }
  bf16x8 kA[2][16];
#pragma unroll
  for (int s = 0; s < 2; ++s)
#pragma unroll
    for (int f = 0; f < 16; ++f)
      kA[s][f] = *reinterpret_cast<const bf16x8*>(
          &kpT[((size_t)bh * 256 + f * 16 + l15) * 64 + s * 32 + g * 8]);
  __syncthreads();
  const __hip_bfloat16* qbase = QKVV + (size_t)b * SEQ * FOURC + h * HDIM;
  const __hip_bfloat16* vbase = qbase + 2 * CH;
  bf16x8 qf[2], vf[2];
#pragma unroll
  for (int s = 0; s < 2; ++s) {
    qf[s] = *reinterpret_cast<const bf16x8*>(
        &qbase[(size_t)(nblk + w * 16 + l15) * FOURC + s * 32 + g * 8]);
    vf[s] = *reinterpret_cast<const bf16x8*>(
        &vbase[(size_t)(nblk + w * 16 + l15) * FOURC + s * 32 + g * 8]);
  }
  for (int c = w; c < 32; c += 4) {
    const int n0 = nblk + c * 16;
    bf16x8 qn[2], vn[2];
    if (c + 4 < 32) {
#pragma unroll
      for (int s = 0; s < 2; ++s) {
        qn[s] = *reinterpret_cast<const bf16x8*>(
            &qbase[(size_t)(n0 + 64 + l15) * FOURC + s * 32 + g * 8]);
        vn[s] = *reinterpret_cast<const bf16x8*>(
            &vbase[(size_t)(n0 + 64 + l15) * FOURC + s * 32 + g * 8]);
      }
    }
    f32x4 o[4] = {};
#pragma unroll
    for (int dt = 0; dt < 4; ++dt) {
      bf16x8 g0 = *reinterpret_cast<const bf16x8*>(&gs[dt * 16 + l15][g * 8]);
      bf16x8 g1 = *reinterpret_cast<const bf16x8*>(&gs[dt * 16 + l15][32 + g * 8]);
      o[dt] = __builtin_amdgcn_mfma_f32_16x16x32_bf16(vf[0], g0, o[dt], 0, 0, 0);
      o[dt] = __builtin_amdgcn_mfma_f32_16x16x32_bf16(vf[1], g1, o[dt], 0, 0, 0);
    }
    f32x4 acc[16] = {};
#pragma unroll
    for (int f = 0; f < 16; ++f) {
      acc[f] = __builtin_amdgcn_mfma_f32_16x16x32_bf16(kA[0][f], qf[0], acc[f], 0, 0, 0);
      acc[f] = __builtin_amdgcn_mfma_f32_16x16x32_bf16(kA[1][f], qf[1], acc[f], 0, 0, 0);
    }
    float m = -3.0e38f;
#pragma unroll
    for (int f = 0; f < 16; ++f)
#pragma unroll
      for (int r = 0; r < 4; ++r) m = fmaxf(m, acc[f][r]);
    m = fmaxf(m, __shfl_xor(m, 16));
    m = fmaxf(m, __shfl_xor(m, 32));
    float sum = 0.f;
#pragma unroll
    for (int f = 0; f < 16; ++f)
#pragma unroll
      for (int r = 0; r < 4; ++r) {
        float e = __expf(acc[f][r] - m);
        acc[f][r] = e; sum += e;
      }
    sum += __shfl_xor(sum, 16);
    sum += __shfl_xor(sum, 32);
    const float rinv = 1.0f / sum;
#pragma unroll
    for (int f = 0; f < 16; ++f) {
      uint2 pw;
      pw.x = packbf2(acc[f][0] * rinv, acc[f][1] * rinv);
      pw.y = packbf2(acc[f][2] * rinv, acc[f][3] * rinv);
      *reinterpret_cast<uint2*>(&ps[w][l15][f * 16 + g * 4]) = pw;
    }
    __builtin_amdgcn_wave_barrier();
#pragma unroll
    for (int s = 0; s < 8; ++s) {
      bf16x8 pa = *reinterpret_cast<const bf16x8*>(&ps[w][l15][s * 32 + g * 8]);
#pragma unroll
      for (int dt = 0; dt < 4; ++dt) {
        bf16x8 vb = *reinterpret_cast<const bf16x8*>(&vs[dt * 16 + l15][s * 32 + g * 8]);
        o[dt] = __builtin_amdgcn_mfma_f32_16x16x32_bf16(pa, vb, o[dt], 0, 0, 0);
      }
    }
#pragma unroll
    for (int dt = 0; dt < 4; ++dt)
#pragma unroll
      for (int r = 0; r < 4; ++r) {
        size_t oo = ((size_t)(b * SEQ + n0 + g * 4 + r)) * CH + h * HDIM + dt * 16 + l15;
        out[oo] = o[dt][r];
      }
    qf[0] = qn[0]; qf[1] = qn[1];
    vf[0] = vn[0]; vf[1] = vn[1];
    __builtin_amdgcn_wave_barrier();
  }
}

extern "C" void kernel_launch(void* const* d_in, const int* in_sizes, int n_in,
                              void* d_out, int out_size, void* d_ws, size_t ws_size,
                              hipStream_t stream) {
  const float* x   = (const float*)d_in[0];
  const float* w   = (const float*)d_in[1];
  const float* sp  = (const float*)d_in[2];
  const float* tca = (const float*)d_in[3];
  const float* tsa = (const float*)d_in[4];
  float* out = (float*)d_out;
  char* ws = (char*)d_ws;

  __hip_bfloat16* qkvv = (__hip_bfloat16*)ws;                  // 134217728
  __hip_bfloat16* wt   = (__hip_bfloat16*)(ws + 134217728);    // 2097152
  __hip_bfloat16* pt   = (__hip_bfloat16*)(ws + 136314880);    // 4194304
  __hip_bfloat16* xb   = (__hip_bfloat16*)(ws + 140509184);    // 33554432 (dead after gemm)
  __hip_bfloat16* gb   = (__hip_bfloat16*)(ws + 140509184);    // 262144, aliases xb
  __hip_bfloat16* kpT  = (__hip_bfloat16*)(ws + 174063616);    // 1048576
  __hip_bfloat16* vpT  = (__hip_bfloat16*)(ws + 175112192);    // 1048576
  // contiguous zeroed region: G | sumsq | raw
  float* G     = (float*)(ws + 176177152);                     // 524288
  float* sumsq = (float*)(ws + 176701440);                     // 16384
  float* raw   = (float*)(ws + 176717824);                     // 4194304

  hipMemsetAsync(G, 0, 524288 + 16384 + 4194304, stream);

  hipLaunchKernelGGL(k_wt, dim3(64, 16), dim3(256), 0, stream, w, wt);
  hipLaunchKernelGGL(k_pt, dim3(256, 8), dim3(256), 0, stream, sp, pt);
  hipLaunchKernelGGL(k_xbf, dim3(8192), dim3(256), 0, stream, x, xb);
  hipLaunchKernelGGL(k_gemm_mfma, dim3(4096), dim3(256), 0, stream, xb, wt, qkvv);
  hipLaunchKernelGGL(k_qkstats, dim3(16, 32), dim3(256), 0, stream, qkvv, pt, G, sumsq, raw);
  hipLaunchKernelGGL(k_epi, dim3(32), dim3(256), 0, stream, sumsq, G, raw, tca, tsa,
                     gb, kpT, vpT);
  hipLaunchKernelGGL(k_xout, dim3(16, 32), dim3(256), 0, stream, qkvv, gb, kpT, vpT, out);
}

// Round 9
// 266.868 us; speedup vs baseline: 1.1871x; 1.1871x over previous
//
#include <hip/hip_runtime.h>
#include <hip/hip_bf16.h>

#define BATCH 4
#define SEQ   8192
#define CH    512
#define NHEAD 8
#define HDIM  64
#define KTOK  256
#define FOURC 2048

typedef __attribute__((ext_vector_type(8))) short bf16x8;
typedef __attribute__((ext_vector_type(4))) float f32x4;

#define GLOAD_LDS16(g, l)                                                      \
  __builtin_amdgcn_global_load_lds(                                            \
      (const __attribute__((address_space(1))) void*)(g),                      \
      (__attribute__((address_space(3))) void*)(l), 16, 0, 0)

__device__ __forceinline__ ushort bf16bits(float f) {
  __hip_bfloat16 b = __float2bfloat16(f);
  return *reinterpret_cast<ushort*>(&b);
}
__device__ __forceinline__ uint packbf2(float lo, float hi) {
  return (uint)bf16bits(lo) | ((uint)bf16bits(hi) << 16);
}

// ---------------- K0: W [512][2048] fp32 -> Wt [2048][512] bf16 ----------------
__global__ __launch_bounds__(256) void k_wt(
    const float* __restrict__ W, __hip_bfloat16* __restrict__ Wt) {
  __shared__ float tile[32][33];
  const int bx = blockIdx.x * 32;
  const int by = blockIdx.y * 32;
  const int t = threadIdx.x;
  const int r = t >> 5, c = t & 31;
#pragma unroll
  for (int it = 0; it < 4; ++it)
    tile[r + it * 8][c] = W[(size_t)(by + r + it * 8) * FOURC + bx + c];
  __syncthreads();
#pragma unroll
  for (int it = 0; it < 4; ++it) {
    int n = r + it * 8;
    Wt[(size_t)(bx + n) * CH + by + c] = __float2bfloat16(tile[c][n]);
  }
}

// ---------------- K0b: P [8192][256] fp32 -> Pt [256][8192] bf16 ----------------
__global__ __launch_bounds__(256) void k_pt(
    const float* __restrict__ P, __hip_bfloat16* __restrict__ Pt) {
  __shared__ float tile[32][33];
  const int n0 = blockIdx.x * 32, k0 = blockIdx.y * 32;
  const int t = threadIdx.x, r = t >> 5, c = t & 31;
#pragma unroll
  for (int i = 0; i < 4; ++i)
    tile[r + i * 8][c] = P[(size_t)(n0 + r + i * 8) * KTOK + k0 + c];
  __syncthreads();
#pragma unroll
  for (int i = 0; i < 4; ++i)
    Pt[(size_t)(k0 + r + i * 8) * SEQ + n0 + c] = __float2bfloat16(tile[c][r + i * 8]);
}

// ---------------- K0c: X fp32 -> Xb bf16 (flat stream) ----------------
__global__ __launch_bounds__(256) void k_xbf(
    const float* __restrict__ X, __hip_bfloat16* __restrict__ Xb) {
  size_t i = ((size_t)blockIdx.x * 256 + threadIdx.x) * 8;
  float4 a = *reinterpret_cast<const float4*>(&X[i]);
  float4 b = *reinterpret_cast<const float4*>(&X[i + 4]);
  ushort tmp[8];
  tmp[0] = bf16bits(a.x); tmp[1] = bf16bits(a.y);
  tmp[2] = bf16bits(a.z); tmp[3] = bf16bits(a.w);
  tmp[4] = bf16bits(b.x); tmp[5] = bf16bits(b.y);
  tmp[6] = bf16bits(b.z); tmp[7] = bf16bits(b.w);
  *reinterpret_cast<uint4*>(&Xb[i]) = *reinterpret_cast<const uint4*>(tmp);
}

// ---------------- K1: qkvv = Xb @ Wt, bf16 MFMA, 3-deep gload_lds pipeline ----------------
__global__ __launch_bounds__(256) void k_gemm_mfma(
    const __hip_bfloat16* __restrict__ Xb, const __hip_bfloat16* __restrict__ Wt,
    __hip_bfloat16* __restrict__ QKVV) {
  __shared__ __align__(16) __hip_bfloat16 As[3][128 * 32];
  __shared__ __align__(16) __hip_bfloat16 Bs[3][128 * 32];
  const int t = threadIdx.x;
  const int wid = t >> 6, lane = t & 63;
  const int bid = blockIdx.x;
  const int xcd = bid & 7;
  const int l = bid >> 3;
  const int bm = (xcd * 32 + (l >> 4)) * 128;
  const int bn = (l & 15) * 128;
  const int wr = wid >> 1, wc = wid & 1;
  const int lrow = lane & 15;
  const int lk = (((lane >> 4) ^ ((lrow >> 1) & 3))) * 8;
  const int srow = lane >> 2;
  const int sk8 = (((lane & 3) ^ ((lane >> 3) & 3))) * 8;
  const int c0 = wid * 2, c1 = wid * 2 + 1;
  f32x4 acc[4][4] = {};

#define STAGE(bufi, kk)                                                         \
  do {                                                                          \
    GLOAD_LDS16(&Xb[(size_t)(bm + c0 * 16 + srow) * CH + (kk) + sk8],           \
                &As[bufi][c0 * 512]);                                           \
    GLOAD_LDS16(&Wt[(size_t)(bn + c0 * 16 + srow) * CH + (kk) + sk8],           \
                &Bs[bufi][c0 * 512]);                                           \
    GLOAD_LDS16(&Xb[(size_t)(bm + c1 * 16 + srow) * CH + (kk) + sk8],           \
                &As[bufi][c1 * 512]);                                           \
    GLOAD_LDS16(&Wt[(size_t)(bn + c1 * 16 + srow) * CH + (kk) + sk8],           \
                &Bs[bufi][c1 * 512]);                                           \
  } while (0)

  STAGE(0, 0);
  STAGE(1, 32);
#pragma unroll
  for (int kt = 0; kt < 16; ++kt) {
    const int cur = kt % 3;
    if (kt < 14) {
      STAGE((kt + 2) % 3, (kt + 2) * 32);
      asm volatile("s_waitcnt vmcnt(8)" ::: "memory");
    } else if (kt == 14) {
      asm volatile("s_waitcnt vmcnt(4)" ::: "memory");
    } else {
      asm volatile("s_waitcnt vmcnt(0)" ::: "memory");
    }
    __builtin_amdgcn_s_barrier();
    bf16x8 af[4], bfr[4];
#pragma unroll
    for (int i = 0; i < 4; ++i)
      af[i] = *reinterpret_cast<const bf16x8*>(&As[cur][(wr * 64 + i * 16 + lrow) * 32 + lk]);
#pragma unroll
    for (int j = 0; j < 4; ++j)
      bfr[j] = *reinterpret_cast<const bf16x8*>(&Bs[cur][(wc * 64 + j * 16 + lrow) * 32 + lk]);
#pragma unroll
    for (int i = 0; i < 4; ++i)
#pragma unroll
      for (int j = 0; j < 4; ++j)
        acc[i][j] = __builtin_amdgcn_mfma_f32_16x16x32_bf16(af[i], bfr[j], acc[i][j], 0, 0, 0);
    asm volatile("s_waitcnt lgkmcnt(0)" ::: "memory");
    __builtin_amdgcn_s_barrier();
  }
#undef STAGE
  const int l4 = (lane >> 4) * 4;
#pragma unroll
  for (int i = 0; i < 4; ++i)
#pragma unroll
    for (int j = 0; j < 4; ++j) {
      int col = bn + wc * 64 + j * 16 + lrow;
#pragma unroll
      for (int r = 0; r < 4; ++r) {
        int row = bm + wr * 64 + i * 16 + l4 + r;
        QKVV[(size_t)row * FOURC + col] = __float2bfloat16(acc[i][j][r]);
      }
    }
}

// ---------------- K3: fused gram + sumsq + k/v projections (swizzled staging) ----------------
// Transpose-stage swizzle: store col = n ^ (((d>>3)&3)<<3); read col-block = g ^ ((row>>3)&3).
__global__ __launch_bounds__(256) void k_qkstats(
    const __hip_bfloat16* __restrict__ QKVV,
    const __hip_bfloat16* __restrict__ Pt,
    float* __restrict__ G, float* __restrict__ sumsq, float* __restrict__ raw) {
  __shared__ __hip_bfloat16 qT[64][40];
  __shared__ __hip_bfloat16 kT[64][40];
  __shared__ __hip_bfloat16 vT[64][40];
  __shared__ __hip_bfloat16 pT[256][40];
  __shared__ float red[32][64];
  const int bh = blockIdx.y, b = bh >> 3, h = bh & 7;
  const int nbase = blockIdx.x * 1024;
  const int t = threadIdx.x, w = t >> 6, lane = t & 63;
  const int l15 = lane & 15, g = lane >> 4;
  const int comp = w >> 1, kh = w & 1;
  const int srow = t >> 3, sdq = (t & 7) * 8;
  const int scol = srow ^ ((t & 3) << 3);      // swizzled store column
  const int prow = t >> 2, poff = (t & 3) * 8;
  // per-fragment read column blocks (invert swizzle)
  int gq[4], gw;
  {
#pragma unroll
    for (int dt = 0; dt < 4; ++dt) gq[dt] = (g ^ (((dt * 16 + l15) >> 3) & 3)) * 8;
    gw = (g ^ (((w * 16 + l15) >> 3) & 3)) * 8;
  }
  f32x4 acc[4][8] = {};
  f32x4 accg[4] = {};
  float sqq[8] = {}, sqk[8] = {};
  uint4 uq, uk, uv, up0, up1, up2, up3;
  {
    size_t gb = (size_t)(b * SEQ + nbase + srow) * FOURC + h * HDIM + sdq;
    uq = *reinterpret_cast<const uint4*>(&QKVV[gb]);
    uk = *reinterpret_cast<const uint4*>(&QKVV[gb + CH]);
    uv = *reinterpret_cast<const uint4*>(&QKVV[gb + 3 * CH]);
    up0 = *reinterpret_cast<const uint4*>(&Pt[(size_t)(0 * 64 + prow) * SEQ + nbase + poff]);
    up1 = *reinterpret_cast<const uint4*>(&Pt[(size_t)(1 * 64 + prow) * SEQ + nbase + poff]);
    up2 = *reinterpret_cast<const uint4*>(&Pt[(size_t)(2 * 64 + prow) * SEQ + nbase + poff]);
    up3 = *reinterpret_cast<const uint4*>(&Pt[(size_t)(3 * 64 + prow) * SEQ + nbase + poff]);
  }
  for (int it = 0; it < 32; ++it) {
    {
      const __hip_bfloat16* hq = reinterpret_cast<const __hip_bfloat16*>(&uq);
      const __hip_bfloat16* hk = reinterpret_cast<const __hip_bfloat16*>(&uk);
      const __hip_bfloat16* hv = reinterpret_cast<const __hip_bfloat16*>(&uv);
#pragma unroll
      for (int j = 0; j < 8; ++j) {
        float fq = __bfloat162float(hq[j]);
        float fk = __bfloat162float(hk[j]);
        sqq[j] = fmaf(fq, fq, sqq[j]);
        sqk[j] = fmaf(fk, fk, sqk[j]);
        qT[sdq + j][scol] = hq[j];
        kT[sdq + j][scol] = hk[j];
        vT[sdq + j][scol] = hv[j];
      }
      *reinterpret_cast<uint4*>(&pT[0 * 64 + prow][poff]) = up0;
      *reinterpret_cast<uint4*>(&pT[1 * 64 + prow][poff]) = up1;
      *reinterpret_cast<uint4*>(&pT[2 * 64 + prow][poff]) = up2;
      *reinterpret_cast<uint4*>(&pT[3 * 64 + prow][poff]) = up3;
    }
    if (it < 31) {
      const int nn = nbase + (it + 1) * 32;
      size_t gb = (size_t)(b * SEQ + nn + srow) * FOURC + h * HDIM + sdq;
      uq = *reinterpret_cast<const uint4*>(&QKVV[gb]);
      uk = *reinterpret_cast<const uint4*>(&QKVV[gb + CH]);
      uv = *reinterpret_cast<const uint4*>(&QKVV[gb + 3 * CH]);
      up0 = *reinterpret_cast<const uint4*>(&Pt[(size_t)(0 * 64 + prow) * SEQ + nn + poff]);
      up1 = *reinterpret_cast<const uint4*>(&Pt[(size_t)(1 * 64 + prow) * SEQ + nn + poff]);
      up2 = *reinterpret_cast<const uint4*>(&Pt[(size_t)(2 * 64 + prow) * SEQ + nn + poff]);
      up3 = *reinterpret_cast<const uint4*>(&Pt[(size_t)(3 * 64 + prow) * SEQ + nn + poff]);
    }
    __syncthreads();
    {
      bf16x8 Aq[4];
#pragma unroll
      for (int dt = 0; dt < 4; ++dt)
        Aq[dt] = *reinterpret_cast<const bf16x8*>(&qT[dt * 16 + l15][gq[dt]]);
      bf16x8 Bk = *reinterpret_cast<const bf16x8*>(&kT[w * 16 + l15][gw]);
#pragma unroll
      for (int dt = 0; dt < 4; ++dt)
        accg[dt] = __builtin_amdgcn_mfma_f32_16x16x32_bf16(Aq[dt], Bk, accg[dt], 0, 0, 0);
    }
    {
      bf16x8 A[4], B[8];
#pragma unroll
      for (int dt = 0; dt < 4; ++dt)
        A[dt] = comp ? *reinterpret_cast<const bf16x8*>(&vT[dt * 16 + l15][gq[dt]])
                     : *reinterpret_cast<const bf16x8*>(&kT[dt * 16 + l15][gq[dt]]);
#pragma unroll
      for (int kt = 0; kt < 8; ++kt)
        B[kt] = *reinterpret_cast<const bf16x8*>(&pT[(kh * 8 + kt) * 16 + l15][g * 8]);
#pragma unroll
      for (int dt = 0; dt < 4; ++dt)
#pragma unroll
        for (int kt = 0; kt < 8; ++kt)
          acc[dt][kt] = __builtin_amdgcn_mfma_f32_16x16x32_bf16(A[dt], B[kt], acc[dt][kt], 0, 0, 0);
    }
    __syncthreads();
  }
#pragma unroll
  for (int j = 0; j < 8; ++j) red[srow][sdq + j] = sqq[j];
  __syncthreads();
  if (t < 64) {
    float tot = 0.f;
#pragma unroll
    for (int r = 0; r < 32; ++r) tot += red[r][t];
    atomicAdd(&sumsq[bh * 64 + t], tot);
  }
  __syncthreads();
#pragma unroll
  for (int j = 0; j < 8; ++j) red[srow][sdq + j] = sqk[j];
  __syncthreads();
  if (t < 64) {
    float tot = 0.f;
#pragma unroll
    for (int r = 0; r < 32; ++r) tot += red[r][t];
    atomicAdd(&sumsq[2048 + bh * 64 + t], tot);
  }
  float* gp = G + (size_t)bh * 4096;
#pragma unroll
  for (int dt = 0; dt < 4; ++dt)
#pragma unroll
    for (int r = 0; r < 4; ++r)
      atomicAdd(&gp[(dt * 16 + g * 4 + r) * 64 + w * 16 + l15], accg[dt][r]);
  float* rp = raw + ((size_t)bh * 2 + comp) * (64 * 256);
#pragma unroll
  for (int dt = 0; dt < 4; ++dt)
#pragma unroll
    for (int kt = 0; kt < 8; ++kt)
#pragma unroll
      for (int r = 0; r < 4; ++r)
        atomicAdd(&rp[(dt * 16 + g * 4 + r) * 256 + (kh * 8 + kt) * 16 + l15],
                  acc[dt][kt][r]);
}

// ---------------- K4: merged epilogue: norms + CA softmax (bf16 out) + projfin ----------------
__global__ __launch_bounds__(256) void k_epi(
    const float* __restrict__ sumsq, const float* __restrict__ G,
    const float* __restrict__ raw, const float* __restrict__ tca,
    const float* __restrict__ tsa, __hip_bfloat16* __restrict__ Gb,
    __hip_bfloat16* __restrict__ kpT, __hip_bfloat16* __restrict__ vpT) {
  __shared__ float iqs[64], iks[64];
  __shared__ float tile[64][65];
  const int bh = blockIdx.x, h = bh & 7;
  const int t = threadIdx.x;
  if (t < 64) {
    iqs[t] = rsqrtf(fmaxf(sumsq[bh * 64 + t], 1e-6f));
    iks[t] = rsqrtf(fmaxf(sumsq[2048 + bh * 64 + t], 1e-6f));
  }
  __syncthreads();
  if (t < 64) {
    const float* row = G + (size_t)bh * 4096 + t * 64;
    const float s0 = iqs[t] * tca[h];
    float vals[64];
    float m = -3.0e38f;
#pragma unroll
    for (int e = 0; e < 64; ++e) {
      float v = row[e] * s0 * iks[e];
      vals[e] = v;
      m = fmaxf(m, v);
    }
    float s = 0.f;
#pragma unroll
    for (int e = 0; e < 64; ++e) { vals[e] = __expf(vals[e] - m); s += vals[e]; }
    float r = 1.0f / s;
#pragma unroll
    for (int e = 0; e < 64; ++e)
      Gb[(size_t)bh * 4096 + t * 64 + e] = __float2bfloat16(vals[e] * r);
  }
  const float ts = tsa[h];
  const float* r0 = raw + (size_t)bh * 2 * 16384;
  for (int kc = 0; kc < 4; ++kc) {
    __syncthreads();
    for (int i = t; i < 4096; i += 256) {
      int d = i >> 6, kk = i & 63;
      tile[d][kk] = r0[d * 256 + kc * 64 + kk];
    }
    __syncthreads();
    for (int i = t; i < 4096; i += 256) {
      int kk = i >> 6, d = i & 63;
      float sc = iqs[d] * iks[d] * ts;
      kpT[(size_t)bh * 16384 + (kc * 64 + kk) * 64 + d] = __float2bfloat16(tile[d][kk] * sc);
    }
  }
  const float* r1 = r0 + 16384;
  for (int i = t; i < 16384; i += 256)
    vpT[(size_t)bh * 16384 + i] = __float2bfloat16(r1[i]);
}

// ---------------- K7: fused output = x_ca + x_sa via MFMA (q/v prefetch) ----------------
__global__ __launch_bounds__(256) void k_xout(
    const __hip_bfloat16* __restrict__ QKVV,
    const __hip_bfloat16* __restrict__ Gb,
    const __hip_bfloat16* __restrict__ kpT,
    const __hip_bfloat16* __restrict__ vpT,
    float* __restrict__ out) {
  __shared__ __hip_bfloat16 vs[64][264];
  __shared__ __hip_bfloat16 ps[4][16][264];
  __shared__ __hip_bfloat16 gs[64][72];
  const int bh = blockIdx.y, b = bh >> 3, h = bh & 7;
  const int nblk = blockIdx.x * 512;
  const int t = threadIdx.x, w = t >> 6, lane = t & 63;
  const int l15 = lane & 15, g = lane >> 4;
  for (int i = t; i < 2048; i += 256) {
    int d = i >> 5, k8 = (i & 31) * 8;
    *reinterpret_cast<uint4*>(&vs[d][k8]) =
        *reinterpret_cast<const uint4*>(&vpT[((size_t)bh * 64 + d) * 256 + k8]);
  }
  for (int i = t; i < 512; i += 256) {
    int row = i >> 3, q = i & 7;
    *reinterpret_cast<uint4*>(&gs[row][q * 8]) =
        *reinterpret_cast<const uint4*>(&Gb[(size_t)bh * 4096 + row * 64 + q * 8]);
  }
  bf16x8 kA[2][16];
#pragma unroll
  for (int s = 0; s < 2; ++s)
#pragma unroll
    for (int f = 0; f < 16; ++f)
      kA[s][f] = *reinterpret_cast<const bf16x8*>(
          &kpT[((size_t)bh * 256 + f * 16 + l15) * 64 + s * 32 + g * 8]);
  __syncthreads();
  const __hip_bfloat16* qbase = QKVV + (size_t)b * SEQ * FOURC + h * HDIM;
  const __hip_bfloat16* vbase = qbase + 2 * CH;
  bf16x8 qf[2], vf[2];
#pragma unroll
  for (int s = 0; s < 2; ++s) {
    qf[s] = *reinterpret_cast<const bf16x8*>(
        &qbase[(size_t)(nblk + w * 16 + l15) * FOURC + s * 32 + g * 8]);
    vf[s] = *reinterpret_cast<const bf16x8*>(
        &vbase[(size_t)(nblk + w * 16 + l15) * FOURC + s * 32 + g * 8]);
  }
  for (int c = w; c < 32; c += 4) {
    const int n0 = nblk + c * 16;
    bf16x8 qn[2], vn[2];
    if (c + 4 < 32) {
#pragma unroll
      for (int s = 0; s < 2; ++s) {
        qn[s] = *reinterpret_cast<const bf16x8*>(
            &qbase[(size_t)(n0 + 64 + l15) * FOURC + s * 32 + g * 8]);
        vn[s] = *reinterpret_cast<const bf16x8*>(
            &vbase[(size_t)(n0 + 64 + l15) * FOURC + s * 32 + g * 8]);
      }
    }
    f32x4 o[4] = {};
#pragma unroll
    for (int dt = 0; dt < 4; ++dt) {
      bf16x8 g0 = *reinterpret_cast<const bf16x8*>(&gs[dt * 16 + l15][g * 8]);
      bf16x8 g1 = *reinterpret_cast<const bf16x8*>(&gs[dt * 16 + l15][32 + g * 8]);
      o[dt] = __builtin_amdgcn_mfma_f32_16x16x32_bf16(vf[0], g0, o[dt], 0, 0, 0);
      o[dt] = __builtin_amdgcn_mfma_f32_16x16x32_bf16(vf[1], g1, o[dt], 0, 0, 0);
    }
    f32x4 acc[16] = {};
#pragma unroll
    for (int f = 0; f < 16; ++f) {
      acc[f] = __builtin_amdgcn_mfma_f32_16x16x32_bf16(kA[0][f], qf[0], acc[f], 0, 0, 0);
      acc[f] = __builtin_amdgcn_mfma_f32_16x16x32_bf16(kA[1][f], qf[1], acc[f], 0, 0, 0);
    }
    float m = -3.0e38f;
#pragma unroll
    for (int f = 0; f < 16; ++f)
#pragma unroll
      for (int r = 0; r < 4; ++r) m = fmaxf(m, acc[f][r]);
    m = fmaxf(m, __shfl_xor(m, 16));
    m = fmaxf(m, __shfl_xor(m, 32));
    float sum = 0.f;
#pragma unroll
    for (int f = 0; f < 16; ++f)
#pragma unroll
      for (int r = 0; r < 4; ++r) {
        float e = __expf(acc[f][r] - m);
        acc[f][r] = e; sum += e;
      }
    sum += __shfl_xor(sum, 16);
    sum += __shfl_xor(sum, 32);
    const float rinv = 1.0f / sum;
#pragma unroll
    for (int f = 0; f < 16; ++f) {
      uint2 pw;
      pw.x = packbf2(acc[f][0] * rinv, acc[f][1] * rinv);
      pw.y = packbf2(acc[f][2] * rinv, acc[f][3] * rinv);
      *reinterpret_cast<uint2*>(&ps[w][l15][f * 16 + g * 4]) = pw;
    }
    __builtin_amdgcn_wave_barrier();
#pragma unroll
    for (int s = 0; s < 8; ++s) {
      bf16x8 pa = *reinterpret_cast<const bf16x8*>(&ps[w][l15][s * 32 + g * 8]);
#pragma unroll
      for (int dt = 0; dt < 4; ++dt) {
        bf16x8 vb = *reinterpret_cast<const bf16x8*>(&vs[dt * 16 + l15][s * 32 + g * 8]);
        o[dt] = __builtin_amdgcn_mfma_f32_16x16x32_bf16(pa, vb, o[dt], 0, 0, 0);
      }
    }
#pragma unroll
    for (int dt = 0; dt < 4; ++dt)
#pragma unroll
      for (int r = 0; r < 4; ++r) {
        size_t oo = ((size_t)(b * SEQ + n0 + g * 4 + r)) * CH + h * HDIM + dt * 16 + l15;
        out[oo] = o[dt][r];
      }
    qf[0] = qn[0]; qf[1] = qn[1];
    vf[0] = vn[0]; vf[1] = vn[1];
    __builtin_amdgcn_wave_barrier();
  }
}

extern "C" void kernel_launch(void* const* d_in, const int* in_sizes, int n_in,
                              void* d_out, int out_size, void* d_ws, size_t ws_size,
                              hipStream_t stream) {
  const float* x   = (const float*)d_in[0];
  const float* w   = (const float*)d_in[1];
  const float* sp  = (const float*)d_in[2];
  const float* tca = (const float*)d_in[3];
  const float* tsa = (const float*)d_in[4];
  float* out = (float*)d_out;
  char* ws = (char*)d_ws;

  __hip_bfloat16* qkvv = (__hip_bfloat16*)ws;                  // 134217728
  __hip_bfloat16* wt   = (__hip_bfloat16*)(ws + 134217728);    // 2097152
  __hip_bfloat16* pt   = (__hip_bfloat16*)(ws + 136314880);    // 4194304
  __hip_bfloat16* xb   = (__hip_bfloat16*)(ws + 140509184);    // 33554432 (dead after gemm)
  __hip_bfloat16* gb   = (__hip_bfloat16*)(ws + 140509184);    // 262144, aliases xb
  __hip_bfloat16* kpT  = (__hip_bfloat16*)(ws + 174063616);    // 1048576
  __hip_bfloat16* vpT  = (__hip_bfloat16*)(ws + 175112192);    // 1048576
  // contiguous zeroed region: G | sumsq | raw
  float* G     = (float*)(ws + 176177152);                     // 524288
  float* sumsq = (float*)(ws + 176701440);                     // 16384
  float* raw   = (float*)(ws + 176717824);                     // 4194304

  hipMemsetAsync(G, 0, 524288 + 16384 + 4194304, stream);

  hipLaunchKernelGGL(k_wt, dim3(64, 16), dim3(256), 0, stream, w, wt);
  hipLaunchKernelGGL(k_pt, dim3(256, 8), dim3(256), 0, stream, sp, pt);
  hipLaunchKernelGGL(k_xbf, dim3(8192), dim3(256), 0, stream, x, xb);
  hipLaunchKernelGGL(k_gemm_mfma, dim3(4096), dim3(256), 0, stream, xb, wt, qkvv);
  hipLaunchKernelGGL(k_qkstats, dim3(8, 32), dim3(256), 0, stream, qkvv, pt, G, sumsq, raw);
  hipLaunchKernelGGL(k_epi, dim3(32), dim3(256), 0, stream, sumsq, G, raw, tca, tsa,
                     gb, kpT, vpT);
  hipLaunchKernelGGL(k_xout, dim3(16, 32), dim3(256), 0, stream, qkvv, gb, kpT, vpT, out);
}